// Round 1
// baseline (1562.238 us; speedup 1.0000x reference)
//
#include <hip/hip_runtime.h>

#define N_NODES 100000
#define N_EDGES 1200000
#define DIM     64

// ---------------------------------------------------------------------------
// deg_i/deg_j init to 1.0f (ws is poisoned 0xAA before every launch)
__global__ void init_deg_kernel(float* __restrict__ deg_i, float* __restrict__ deg_j) {
    int i = blockIdx.x * blockDim.x + threadIdx.x;
    if (i < N_NODES) { deg_i[i] = 1.0f; deg_j[i] = 1.0f; }
}

// ---------------------------------------------------------------------------
// xW = x @ W.T + b.  W^T staged in LDS (sWt[k*64+d] = W[d*64+k]) so a wave
// (lanes = d) reads consecutive LDS addresses per k (conflict-free).
// 4 rows per thread amortizes the LDS read over 4 FMAs.
__global__ void linear_kernel(const float* __restrict__ x, const float* __restrict__ W,
                              const float* __restrict__ b, float* __restrict__ xw) {
    __shared__ float sWt[DIM * DIM];
    for (int i = threadIdx.x; i < DIM * DIM; i += blockDim.x) {
        int d = i / DIM, k = i % DIM;
        sWt[k * DIM + d] = W[i];
    }
    __syncthreads();

    int d      = threadIdx.x & 63;
    int waveId = threadIdx.x >> 6;                    // 0..3
    int row    = blockIdx.x * 16 + waveId * 4;        // 16 rows/block, exact: 6250 blocks
    if (row + 3 >= N_NODES && row >= N_NODES) return; // N divisible by 16, so never taken

    const float* x0 = x + (size_t)(row + 0) * DIM;
    const float* x1 = x + (size_t)(row + 1) * DIM;
    const float* x2 = x + (size_t)(row + 2) * DIM;
    const float* x3 = x + (size_t)(row + 3) * DIM;

    float bd = b[d];
    float a0 = bd, a1 = bd, a2 = bd, a3 = bd;
    #pragma unroll
    for (int k = 0; k < DIM; k++) {
        float w = sWt[k * DIM + d];
        a0 = fmaf(x0[k], w, a0);
        a1 = fmaf(x1[k], w, a1);
        a2 = fmaf(x2[k], w, a2);
        a3 = fmaf(x3[k], w, a3);
    }
    xw[(size_t)(row + 0) * DIM + d] = a0;
    xw[(size_t)(row + 1) * DIM + d] = a1;
    xw[(size_t)(row + 2) * DIM + d] = a2;
    xw[(size_t)(row + 3) * DIM + d] = a3;
}

// ---------------------------------------------------------------------------
// deg_i[row[e]] += 1; deg_j[col[e]] += 1  (float atomics, L2-resident)
__global__ void degree_kernel(const int* __restrict__ row, const int* __restrict__ col,
                              float* __restrict__ deg_i, float* __restrict__ deg_j) {
    int e = blockIdx.x * blockDim.x + threadIdx.x;
    if (e >= N_EDGES) return;
    atomicAdd(&deg_i[row[e]], 1.0f);
    atomicAdd(&deg_j[col[e]], 1.0f);
}

// deg -> deg^-0.5 in place
__global__ void rsqrt_kernel(float* __restrict__ deg_i, float* __restrict__ deg_j) {
    int i = blockIdx.x * blockDim.x + threadIdx.x;
    if (i < N_NODES) {
        deg_i[i] = rsqrtf(deg_i[i]);
        deg_j[i] = rsqrtf(deg_j[i]);
    }
}

// ---------------------------------------------------------------------------
// agg[row[e]] += val_e * (xw[col[e]] + edge_attr[e]); 16 threads/edge, each
// owns a float4 slice of D=64.  agg lives in d_out (pre-zeroed).
__global__ void scatter_kernel(const int* __restrict__ row, const int* __restrict__ col,
                               const float* __restrict__ edge_attr,
                               const float* __restrict__ xw,
                               const float* __restrict__ dinv_i,
                               const float* __restrict__ dinv_j,
                               float* __restrict__ agg) {
    long gid = (long)blockIdx.x * blockDim.x + threadIdx.x;
    int e = (int)(gid >> 4);
    if (e >= N_EDGES) return;
    int q = ((int)gid & 15) << 2;   // d offset: 0,4,...,60

    int r = row[e];
    int c = col[e];
    float val = dinv_i[r] * dinv_j[c];

    const float4 ea = *(const float4*)(edge_attr + (size_t)e * DIM + q);
    const float4 xv = *(const float4*)(xw + (size_t)c * DIM + q);
    float* dst = agg + (size_t)r * DIM + q;
    atomicAdd(dst + 0, val * (ea.x + xv.x));
    atomicAdd(dst + 1, val * (ea.y + xv.y));
    atomicAdd(dst + 2, val * (ea.z + xv.z));
    atomicAdd(dst + 3, val * (ea.w + xv.w));
}

// ---------------------------------------------------------------------------
// out = relu(agg) + relu(xw + root) * (dinv_i*dinv_j)   (in place on d_out)
__global__ void final_kernel(const float* __restrict__ xw, const float* __restrict__ root,
                             const float* __restrict__ dinv_i,
                             const float* __restrict__ dinv_j,
                             float* __restrict__ out) {
    int gid = blockIdx.x * blockDim.x + threadIdx.x;
    if (gid >= N_NODES * DIM) return;
    int n = gid >> 6;
    int d = gid & 63;
    float s   = dinv_i[n] * dinv_j[n];
    float agg = out[gid];
    float xv  = xw[gid] + root[d];
    out[gid]  = fmaxf(agg, 0.0f) + fmaxf(xv, 0.0f) * s;
}

// ---------------------------------------------------------------------------
extern "C" void kernel_launch(void* const* d_in, const int* in_sizes, int n_in,
                              void* d_out, int out_size, void* d_ws, size_t ws_size,
                              hipStream_t stream) {
    const float* x         = (const float*)d_in[0];
    const int*   edge_idx  = (const int*)d_in[1];   // (2, E) int32
    const float* edge_attr = (const float*)d_in[2];
    const float* W         = (const float*)d_in[3];
    const float* b         = (const float*)d_in[4];
    const float* root_emb  = (const float*)d_in[5];
    float*       out       = (float*)d_out;

    const int* row = edge_idx;
    const int* col = edge_idx + N_EDGES;

    // workspace layout (floats): xw[N*D] | deg_i[N] | deg_j[N]
    float* xw    = (float*)d_ws;
    float* deg_i = xw + (size_t)N_NODES * DIM;
    float* deg_j = deg_i + N_NODES;

    // zero agg accumulator (lives in d_out)
    hipMemsetAsync(d_out, 0, (size_t)out_size * sizeof(float), stream);

    init_deg_kernel<<<(N_NODES + 255) / 256, 256, 0, stream>>>(deg_i, deg_j);

    linear_kernel<<<N_NODES / 16, 256, 0, stream>>>(x, W, b, xw);

    degree_kernel<<<(N_EDGES + 255) / 256, 256, 0, stream>>>(row, col, deg_i, deg_j);

    rsqrt_kernel<<<(N_NODES + 255) / 256, 256, 0, stream>>>(deg_i, deg_j);

    long scatter_threads = (long)N_EDGES * 16;
    scatter_kernel<<<(int)((scatter_threads + 255) / 256), 256, 0, stream>>>(
        row, col, edge_attr, xw, deg_i, deg_j, out);

    final_kernel<<<(N_NODES * DIM + 255) / 256, 256, 0, stream>>>(
        xw, root_emb, deg_i, deg_j, out);
}

// Round 2
// 875.096 us; speedup vs baseline: 1.7852x; 1.7852x over previous
//
#include <hip/hip_runtime.h>

#define N_NODES 100000
#define N_EDGES 1200000
#define DIM     64
#define SCAN_B  256
#define NB      ((N_NODES + SCAN_B - 1) / SCAN_B)   // 391 scan blocks

// ---------------------------------------------------------------------------
// xW = x @ W.T + b.  W^T staged in LDS; 4 rows/thread.
__global__ void linear_kernel(const float* __restrict__ x, const float* __restrict__ W,
                              const float* __restrict__ b, float* __restrict__ xw) {
    __shared__ float sWt[DIM * DIM];
    for (int i = threadIdx.x; i < DIM * DIM; i += blockDim.x) {
        int d = i / DIM, k = i % DIM;
        sWt[k * DIM + d] = W[i];
    }
    __syncthreads();

    int d      = threadIdx.x & 63;
    int waveId = threadIdx.x >> 6;
    int row    = blockIdx.x * 16 + waveId * 4;

    const float* x0 = x + (size_t)(row + 0) * DIM;
    const float* x1 = x + (size_t)(row + 1) * DIM;
    const float* x2 = x + (size_t)(row + 2) * DIM;
    const float* x3 = x + (size_t)(row + 3) * DIM;

    float bd = b[d];
    float a0 = bd, a1 = bd, a2 = bd, a3 = bd;
    #pragma unroll
    for (int k = 0; k < DIM; k++) {
        float w = sWt[k * DIM + d];
        a0 = fmaf(x0[k], w, a0);
        a1 = fmaf(x1[k], w, a1);
        a2 = fmaf(x2[k], w, a2);
        a3 = fmaf(x3[k], w, a3);
    }
    xw[(size_t)(row + 0) * DIM + d] = a0;
    xw[(size_t)(row + 1) * DIM + d] = a1;
    xw[(size_t)(row + 2) * DIM + d] = a2;
    xw[(size_t)(row + 3) * DIM + d] = a3;
}

// ---------------------------------------------------------------------------
// integer degree counts for row (dst) and col (src) endpoints
__global__ void count_kernel(const int* __restrict__ row, const int* __restrict__ col,
                             int* __restrict__ cnt_r, int* __restrict__ cnt_c) {
    int e = blockIdx.x * blockDim.x + threadIdx.x;
    if (e >= N_EDGES) return;
    atomicAdd(&cnt_r[row[e]], 1);
    atomicAdd(&cnt_c[col[e]], 1);
}

// dinv = rsqrt(1 + cnt)
__global__ void rsqrt_kernel(const int* __restrict__ cnt_r, const int* __restrict__ cnt_c,
                             float* __restrict__ dinv_i, float* __restrict__ dinv_j) {
    int i = blockIdx.x * blockDim.x + threadIdx.x;
    if (i < N_NODES) {
        dinv_i[i] = rsqrtf(1.0f + (float)cnt_r[i]);
        dinv_j[i] = rsqrtf(1.0f + (float)cnt_c[i]);
    }
}

// ---------------------------------------------------------------------------
// 3-phase exclusive scan of cnt_r -> offsets
__global__ void scan_a(const int* __restrict__ cnt, int* __restrict__ offsets,
                       int* __restrict__ partials) {
    __shared__ int s[SCAN_B];
    int t = threadIdx.x;
    int i = blockIdx.x * SCAN_B + t;
    int v = (i < N_NODES) ? cnt[i] : 0;
    s[t] = v;
    __syncthreads();
    for (int off = 1; off < SCAN_B; off <<= 1) {
        int add = (t >= off) ? s[t - off] : 0;
        __syncthreads();
        s[t] += add;
        __syncthreads();
    }
    if (i < N_NODES) offsets[i] = s[t] - v;          // exclusive
    if (t == SCAN_B - 1) partials[blockIdx.x] = s[t]; // block total
}

__global__ void scan_b(int* __restrict__ partials) {  // single block, 512 threads
    __shared__ int s[512];
    int t = threadIdx.x;
    int v = (t < NB) ? partials[t] : 0;
    s[t] = v;
    __syncthreads();
    for (int off = 1; off < 512; off <<= 1) {
        int add = (t >= off) ? s[t - off] : 0;
        __syncthreads();
        s[t] += add;
        __syncthreads();
    }
    if (t < NB) partials[t] = s[t] - v;              // exclusive block offsets
}

__global__ void scan_c(int* __restrict__ offsets, const int* __restrict__ partials,
                       int* __restrict__ cursor) {
    int i = blockIdx.x * SCAN_B + threadIdx.x;
    if (i < N_NODES) {
        int o = offsets[i] + partials[blockIdx.x];
        offsets[i] = o;
        cursor[i]  = o;
    }
}

// bin edge ids by destination row -> CSR
__global__ void bin_kernel(const int* __restrict__ row, int* __restrict__ cursor,
                           int* __restrict__ edge_ids) {
    int e = blockIdx.x * blockDim.x + threadIdx.x;
    if (e >= N_EDGES) return;
    int pos = atomicAdd(&cursor[row[e]], 1);
    edge_ids[pos] = e;
}

// ---------------------------------------------------------------------------
// One wave per node: lane = feature dim. Register accumulation, no atomics.
// Fused epilogue: out = relu(agg) + relu(xw + root) * dinv_i*dinv_j.
__global__ __launch_bounds__(256) void gather_kernel(
        const int* __restrict__ offsets, const int* __restrict__ cnt_r,
        const int* __restrict__ edge_ids, const int* __restrict__ col,
        const float* __restrict__ edge_attr, const float* __restrict__ xw,
        const float* __restrict__ dinv_i, const float* __restrict__ dinv_j,
        const float* __restrict__ root, float* __restrict__ out) {
    int lane = threadIdx.x & 63;
    int n = blockIdx.x * 4 + (threadIdx.x >> 6);
    if (n >= N_NODES) return;

    int   start = offsets[n];
    int   cnt   = cnt_r[n];
    float di    = dinv_i[n];

    float acc = 0.0f;
    for (int k = 0; k < cnt; ++k) {
        int   e   = edge_ids[start + k];
        int   c   = col[e];
        float val = di * dinv_j[c];
        float m   = edge_attr[(size_t)e * DIM + lane] + xw[(size_t)c * DIM + lane];
        acc = fmaf(val, m, acc);
    }

    float s  = di * dinv_j[n];
    float xv = xw[(size_t)n * DIM + lane] + root[lane];
    out[(size_t)n * DIM + lane] = fmaxf(acc, 0.0f) + fmaxf(xv, 0.0f) * s;
}

// ---------------------------------------------------------------------------
extern "C" void kernel_launch(void* const* d_in, const int* in_sizes, int n_in,
                              void* d_out, int out_size, void* d_ws, size_t ws_size,
                              hipStream_t stream) {
    const float* x         = (const float*)d_in[0];
    const int*   edge_idx  = (const int*)d_in[1];   // (2, E) int32
    const float* edge_attr = (const float*)d_in[2];
    const float* W         = (const float*)d_in[3];
    const float* b         = (const float*)d_in[4];
    const float* root_emb  = (const float*)d_in[5];
    float*       out       = (float*)d_out;

    const int* row = edge_idx;
    const int* col = edge_idx + N_EDGES;

    // workspace layout:
    // xw[N*D] f32 | cnt_r[N] i32 | cnt_c[N] i32 | dinv_i[N] | dinv_j[N]
    // | offsets[N] i32 | cursor[N] i32 | partials[1024] i32 | edge_ids[E] i32
    char* ws = (char*)d_ws;
    float* xw       = (float*)ws;                         ws += (size_t)N_NODES * DIM * 4;
    int*   cnt_r    = (int*)ws;                           ws += (size_t)N_NODES * 4;
    int*   cnt_c    = (int*)ws;                           ws += (size_t)N_NODES * 4;
    float* dinv_i   = (float*)ws;                         ws += (size_t)N_NODES * 4;
    float* dinv_j   = (float*)ws;                         ws += (size_t)N_NODES * 4;
    int*   offsets  = (int*)ws;                           ws += (size_t)N_NODES * 4;
    int*   cursor   = (int*)ws;                           ws += (size_t)N_NODES * 4;
    int*   partials = (int*)ws;                           ws += 1024 * 4;
    int*   edge_ids = (int*)ws;                           ws += (size_t)N_EDGES * 4;

    // zero the two count arrays (contiguous)
    hipMemsetAsync(cnt_r, 0, (size_t)N_NODES * 2 * sizeof(int), stream);

    linear_kernel<<<N_NODES / 16, 256, 0, stream>>>(x, W, b, xw);

    count_kernel<<<(N_EDGES + 255) / 256, 256, 0, stream>>>(row, col, cnt_r, cnt_c);

    rsqrt_kernel<<<(N_NODES + 255) / 256, 256, 0, stream>>>(cnt_r, cnt_c, dinv_i, dinv_j);

    scan_a<<<NB, SCAN_B, 0, stream>>>(cnt_r, offsets, partials);
    scan_b<<<1, 512, 0, stream>>>(partials);
    scan_c<<<NB, SCAN_B, 0, stream>>>(offsets, partials, cursor);

    bin_kernel<<<(N_EDGES + 255) / 256, 256, 0, stream>>>(row, cursor, edge_ids);

    gather_kernel<<<(N_NODES + 3) / 4, 256, 0, stream>>>(
        offsets, cnt_r, edge_ids, col, edge_attr, xw, dinv_i, dinv_j, root_emb, out);
}

// Round 3
// 666.004 us; speedup vs baseline: 2.3457x; 1.3139x over previous
//
#include <hip/hip_runtime.h>

#define N_NODES 100000
#define N_EDGES 1200000
#define DIM     64
#define SCAN_B  256
#define NB      ((N_NODES + SCAN_B - 1) / SCAN_B)   // 391 scan blocks

typedef unsigned short ushort_t;

__device__ inline float bf2f(ushort_t u) {
    return __uint_as_float(((unsigned int)u) << 16);
}
__device__ inline ushort_t f2bf(float f) {
    // round-to-nearest-even bf16
    unsigned int x = __float_as_uint(f);
    unsigned int r = x + 0x7fff + ((x >> 16) & 1);
    return (ushort_t)(r >> 16);
}

// ---------------------------------------------------------------------------
// xW = x @ W.T + b  ->  bf16 output.
// Block = 256 threads (4 waves), 16 rows/block. x rows staged in LDS via
// coalesced float4; W^T staged with +1 padding (conflict-free stores/loads).
__global__ __launch_bounds__(256) void linear_kernel(
        const float* __restrict__ x, const float* __restrict__ W,
        const float* __restrict__ b, ushort_t* __restrict__ xwb) {
    __shared__ float sWt[DIM * (DIM + 1)];   // sWt[k*(65)+d] = W[d*64+k]
    __shared__ float sx[16][DIM];

    int t = threadIdx.x;
    int row0 = blockIdx.x * 16;

    // stage W^T (4096 elems / 256 threads = 16 each)
    for (int i = t; i < DIM * DIM; i += 256) {
        int d = i >> 6, k = i & 63;
        sWt[k * (DIM + 1) + d] = W[i];
    }
    // stage 16 x rows: thread t -> row t/16, dims (t%16)*4..+3
    {
        int lr = t >> 4, off = (t & 15) << 2;
        const float4 v = *(const float4*)(x + (size_t)(row0 + lr) * DIM + off);
        sx[lr][off + 0] = v.x; sx[lr][off + 1] = v.y;
        sx[lr][off + 2] = v.z; sx[lr][off + 3] = v.w;
    }
    __syncthreads();

    int d      = t & 63;
    int waveId = t >> 6;
    int r0     = waveId * 4;          // wave handles local rows r0..r0+3

    float bd = b[d];
    float a0 = bd, a1 = bd, a2 = bd, a3 = bd;
    const float2* x0 = (const float2*)sx[r0 + 0];
    const float2* x1 = (const float2*)sx[r0 + 1];
    const float2* x2 = (const float2*)sx[r0 + 2];
    const float2* x3 = (const float2*)sx[r0 + 3];
    #pragma unroll
    for (int k2 = 0; k2 < DIM / 2; k2++) {
        float w0 = sWt[(2 * k2 + 0) * (DIM + 1) + d];
        float w1 = sWt[(2 * k2 + 1) * (DIM + 1) + d];
        float2 v0 = x0[k2], v1 = x1[k2], v2 = x2[k2], v3 = x3[k2];
        a0 = fmaf(v0.x, w0, a0); a0 = fmaf(v0.y, w1, a0);
        a1 = fmaf(v1.x, w0, a1); a1 = fmaf(v1.y, w1, a1);
        a2 = fmaf(v2.x, w0, a2); a2 = fmaf(v2.y, w1, a2);
        a3 = fmaf(v3.x, w0, a3); a3 = fmaf(v3.y, w1, a3);
    }
    size_t base = (size_t)(row0 + r0) * DIM + d;
    xwb[base + 0 * DIM] = f2bf(a0);
    xwb[base + 1 * DIM] = f2bf(a1);
    xwb[base + 2 * DIM] = f2bf(a2);
    xwb[base + 3 * DIM] = f2bf(a3);
}

// ---------------------------------------------------------------------------
// integer degree counts; 4 edges/thread via int4
__global__ void count_kernel(const int* __restrict__ row, const int* __restrict__ col,
                             int* __restrict__ cnt_r, int* __restrict__ cnt_c) {
    int i = blockIdx.x * blockDim.x + threadIdx.x;
    if (i * 4 >= N_EDGES) return;
    int4 r4 = ((const int4*)row)[i];
    int4 c4 = ((const int4*)col)[i];
    atomicAdd(&cnt_r[r4.x], 1); atomicAdd(&cnt_r[r4.y], 1);
    atomicAdd(&cnt_r[r4.z], 1); atomicAdd(&cnt_r[r4.w], 1);
    atomicAdd(&cnt_c[c4.x], 1); atomicAdd(&cnt_c[c4.y], 1);
    atomicAdd(&cnt_c[c4.z], 1); atomicAdd(&cnt_c[c4.w], 1);
}

// ---------------------------------------------------------------------------
// scan phase A (+ fused dinv computation)
__global__ void scan_a(const int* __restrict__ cnt_r, const int* __restrict__ cnt_c,
                       int* __restrict__ offsets, int* __restrict__ partials,
                       float* __restrict__ dinv_i, float* __restrict__ dinv_j) {
    __shared__ int s[SCAN_B];
    int t = threadIdx.x;
    int i = blockIdx.x * SCAN_B + t;
    int v = (i < N_NODES) ? cnt_r[i] : 0;
    if (i < N_NODES) {
        dinv_i[i] = rsqrtf(1.0f + (float)v);
        dinv_j[i] = rsqrtf(1.0f + (float)cnt_c[i]);
    }
    s[t] = v;
    __syncthreads();
    for (int off = 1; off < SCAN_B; off <<= 1) {
        int add = (t >= off) ? s[t - off] : 0;
        __syncthreads();
        s[t] += add;
        __syncthreads();
    }
    if (i < N_NODES) offsets[i] = s[t] - v;           // exclusive
    if (t == SCAN_B - 1) partials[blockIdx.x] = s[t]; // block total
}

__global__ void scan_b(int* __restrict__ partials) {  // single block, 512 threads
    __shared__ int s[512];
    int t = threadIdx.x;
    int v = (t < NB) ? partials[t] : 0;
    s[t] = v;
    __syncthreads();
    for (int off = 1; off < 512; off <<= 1) {
        int add = (t >= off) ? s[t - off] : 0;
        __syncthreads();
        s[t] += add;
        __syncthreads();
    }
    if (t < NB) partials[t] = s[t] - v;
}

__global__ void scan_c(int* __restrict__ offsets, const int* __restrict__ partials,
                       int* __restrict__ cursor) {
    int i = blockIdx.x * SCAN_B + threadIdx.x;
    if (i < N_NODES) {
        int o = offsets[i] + partials[blockIdx.x];
        offsets[i] = o;
        cursor[i]  = o;
    }
}

// ---------------------------------------------------------------------------
// bin edges by dst -> rec[pos] = {e, c}, valr[pos] = dinv_i[r]*dinv_j[c]
__global__ void bin_kernel(const int* __restrict__ row, const int* __restrict__ col,
                           const float* __restrict__ dinv_i,
                           const float* __restrict__ dinv_j,
                           int* __restrict__ cursor,
                           int2* __restrict__ rec, float* __restrict__ valr) {
    int e = blockIdx.x * blockDim.x + threadIdx.x;
    if (e >= N_EDGES) return;
    int r = row[e], c = col[e];
    int pos = atomicAdd(&cursor[r], 1);
    rec[pos]  = make_int2(e, c);
    valr[pos] = dinv_i[r] * dinv_j[c];
}

// ---------------------------------------------------------------------------
// Gather v2: one wave per node; 4 edge-groups of 16 lanes; each lane owns a
// float4 slice of D. 4 concurrent edge streams + record prefetch. Butterfly
// reduction across groups; fused epilogue.
__global__ __launch_bounds__(256) void gather_kernel(
        const int* __restrict__ offsets, const int* __restrict__ cnt_r,
        const int2* __restrict__ rec, const float* __restrict__ valr,
        const float* __restrict__ edge_attr, const ushort_t* __restrict__ xwb,
        const float* __restrict__ dinv_i, const float* __restrict__ dinv_j,
        const float* __restrict__ root, float* __restrict__ out) {
    int lane = threadIdx.x & 63;
    int g    = lane >> 4;          // edge group 0..3
    int q    = (lane & 15) << 2;   // dim offset 0,4,...,60
    int n    = blockIdx.x * 4 + (threadIdx.x >> 6);

    int start = offsets[n];
    int cnt   = cnt_r[n];

    float4 acc = make_float4(0.f, 0.f, 0.f, 0.f);
    int k = g;
    if (k < cnt) {
        int2  rc = rec[start + k];
        float vv = valr[start + k];
        while (true) {
            int  kn   = k + 4;
            bool more = kn < cnt;
            int2 rcn; float vvn;
            if (more) { rcn = rec[start + kn]; vvn = valr[start + kn]; }
            const float4  ea = *(const float4*)(edge_attr + (size_t)rc.x * DIM + q);
            const ushort4 xu = *(const ushort4*)(xwb + (size_t)rc.y * DIM + q);
            acc.x = fmaf(vv, ea.x + bf2f(xu.x), acc.x);
            acc.y = fmaf(vv, ea.y + bf2f(xu.y), acc.y);
            acc.z = fmaf(vv, ea.z + bf2f(xu.z), acc.z);
            acc.w = fmaf(vv, ea.w + bf2f(xu.w), acc.w);
            if (!more) break;
            k = kn; rc = rcn; vv = vvn;
        }
    }

    // reduce the 4 groups (butterfly over lane bits 4,5)
    acc.x += __shfl_xor(acc.x, 16); acc.y += __shfl_xor(acc.y, 16);
    acc.z += __shfl_xor(acc.z, 16); acc.w += __shfl_xor(acc.w, 16);
    acc.x += __shfl_xor(acc.x, 32); acc.y += __shfl_xor(acc.y, 32);
    acc.z += __shfl_xor(acc.z, 32); acc.w += __shfl_xor(acc.w, 32);

    if ((lane >> 4) == 0) {  // group 0 writes
        float s = dinv_i[n] * dinv_j[n];
        const ushort4 xu = *(const ushort4*)(xwb + (size_t)n * DIM + q);
        const float4  rt = *(const float4*)(root + q);
        float4 o;
        o.x = fmaxf(acc.x, 0.f) + fmaxf(bf2f(xu.x) + rt.x, 0.f) * s;
        o.y = fmaxf(acc.y, 0.f) + fmaxf(bf2f(xu.y) + rt.y, 0.f) * s;
        o.z = fmaxf(acc.z, 0.f) + fmaxf(bf2f(xu.z) + rt.z, 0.f) * s;
        o.w = fmaxf(acc.w, 0.f) + fmaxf(bf2f(xu.w) + rt.w, 0.f) * s;
        *(float4*)(out + (size_t)n * DIM + q) = o;
    }
}

// ---------------------------------------------------------------------------
extern "C" void kernel_launch(void* const* d_in, const int* in_sizes, int n_in,
                              void* d_out, int out_size, void* d_ws, size_t ws_size,
                              hipStream_t stream) {
    const float* x         = (const float*)d_in[0];
    const int*   edge_idx  = (const int*)d_in[1];
    const float* edge_attr = (const float*)d_in[2];
    const float* W         = (const float*)d_in[3];
    const float* b         = (const float*)d_in[4];
    const float* root_emb  = (const float*)d_in[5];
    float*       out       = (float*)d_out;

    const int* row = edge_idx;
    const int* col = edge_idx + N_EDGES;

    // workspace: xwb[N*D] bf16 | cnt_r,cnt_c,dinv_i,dinv_j,offsets,cursor [N] |
    //            partials[1024] | rec[E] int2 | valr[E] f32   (~29.6 MB)
    char* ws = (char*)d_ws;
    ushort_t* xwb      = (ushort_t*)ws;   ws += (size_t)N_NODES * DIM * 2;
    int*      cnt_r    = (int*)ws;        ws += (size_t)N_NODES * 4;
    int*      cnt_c    = (int*)ws;        ws += (size_t)N_NODES * 4;
    float*    dinv_i   = (float*)ws;      ws += (size_t)N_NODES * 4;
    float*    dinv_j   = (float*)ws;      ws += (size_t)N_NODES * 4;
    int*      offsets  = (int*)ws;        ws += (size_t)N_NODES * 4;
    int*      cursor   = (int*)ws;        ws += (size_t)N_NODES * 4;
    int*      partials = (int*)ws;        ws += 1024 * 4;
    int2*     rec      = (int2*)ws;       ws += (size_t)N_EDGES * 8;
    float*    valr     = (float*)ws;      ws += (size_t)N_EDGES * 4;

    hipMemsetAsync(cnt_r, 0, (size_t)N_NODES * 2 * sizeof(int), stream);

    linear_kernel<<<N_NODES / 16, 256, 0, stream>>>(x, W, b, xwb);

    count_kernel<<<(N_EDGES / 4 + 255) / 256, 256, 0, stream>>>(row, col, cnt_r, cnt_c);

    scan_a<<<NB, SCAN_B, 0, stream>>>(cnt_r, cnt_c, offsets, partials, dinv_i, dinv_j);
    scan_b<<<1, 512, 0, stream>>>(partials);
    scan_c<<<NB, SCAN_B, 0, stream>>>(offsets, partials, cursor);

    bin_kernel<<<(N_EDGES + 255) / 256, 256, 0, stream>>>(
        row, col, dinv_i, dinv_j, cursor, rec, valr);

    gather_kernel<<<N_NODES / 4, 256, 0, stream>>>(
        offsets, cnt_r, rec, valr, edge_attr, xwb, dinv_i, dinv_j, root_emb, out);
}